// Round 16
// baseline (57.825 us; speedup 1.0000x reference)
//
#include <hip/hip_runtime.h>
#include <cstdint>
#include <cstddef>

// ---- problem constants ----
static constexpr int BATCH = 32;
static constexpr int CIN   = 3;
static constexpr int HIN   = 224, WIN = 224;
static constexpr int COUT  = 64;
static constexpr int HOUT  = 56, WOUT = 56;
static constexpr int NPIX  = HOUT * WOUT;     // 3136
static constexpr int NEXP  = 8;
static constexpr int KROWS = 21;              // ci*7 + kh
static constexpr int NKS   = 6;               // K-steps of 32
static constexpr int NGRP  = 28;              // 2-oh-row groups per image (112 px)
static constexpr int PWL   = 232;             // window row length (ushorts): 4+224+4
static constexpr int WR    = 11;              // window rows per ci (2*4 + 3)
static constexpr int NTILE = NPIX / 16;       // 196
static constexpr float LN_EPS_F = 1e-6f;

// fragment-coalesced weight buffer: [e(9)][f(4)][ks(6)][lane(64)][8]
static constexpr int PW3_ELEMS = 9 * 4 * 6 * 64 * 8;   // 110592

// k_pre partition: gate partial sums (768) + weight repack (432)
static constexpr int N_GPART  = BATCH * CIN * 8;                  // 768
static constexpr int N_REPACK = (PW3_ELEMS + 255) / 256;          // 432

// scratch requirement: [b][tile][co][px16] f32
static constexpr size_t WS_NEED = (size_t)BATCH * NTILE * COUT * 16 * 4;  // 25.7 MB

typedef __bf16 bf16x8 __attribute__((ext_vector_type(8)));
typedef float  f32x4  __attribute__((ext_vector_type(4)));

// ---- device-global scratch ----
__device__ __align__(16) ushort g_pw3[PW3_ELEMS];   // bf16 weights, fragment order
__device__ float g_gatepart[BATCH * CIN * 8];       // partial plane sums

__device__ __forceinline__ ushort f2bf(float f) {
  uint u = __float_as_uint(f);
  uint r = (u + 0x7FFFu + ((u >> 16) & 1u)) >> 16;  // RNE
  return (ushort)r;
}

// ---------------- kernel 1: gate partial sums (0..767) / repack (768..1199) ---
__global__ __launch_bounds__(256) void k_pre(const float* __restrict__ x,
                                             const float* __restrict__ eW,
                                             const float* __restrict__ sW) {
  const int bid = blockIdx.x;
  if (bid < N_GPART) {
    const int plane = bid >> 3;
    const int slice = bid & 7;
    const float4* p4 = reinterpret_cast<const float4*>(x + (size_t)plane * (HIN * WIN));
    float s = 0.f;
    const int i0 = slice * 1568;                // 12544/8 float4 per slice
    for (int i = i0 + (int)threadIdx.x; i < i0 + 1568; i += 256) {
      const float4 v = p4[i];
      s += v.x + v.y + v.z + v.w;
    }
    __shared__ float red[256];
    red[threadIdx.x] = s;
    __syncthreads();
    for (int off = 128; off > 0; off >>= 1) {
      if ((int)threadIdx.x < off) red[threadIdx.x] += red[threadIdx.x + off];
      __syncthreads();
    }
    if (threadIdx.x == 0) g_gatepart[bid] = red[0];
  } else {
    // repack -> fragment order: idx = ((e*4+f)*6+ks)*512 + lane*8 + j
    const int idx = (bid - N_GPART) * 256 + threadIdx.x;
    if (idx >= PW3_ELEMS) return;
    const int j    = idx & 7;
    const int lane = (idx >> 3) & 63;
    const int ks   = (idx >> 9) % 6;
    const int fe   = idx / (512 * 6);   // e*4 + f
    const int f    = fe & 3;
    const int e    = fe >> 2;
    const int m    = lane >> 4;
    const int colA = lane & 15;
    const int co   = f * 16 + colA;
    const int r    = ks * 4 + m;
    float v = 0.f;
    if (j >= 1 && r < KROWS) {
      const int k = r * 7 + (j - 1);
      v = (e < 8) ? eW[(size_t)(e * COUT + co) * 147 + k]
                  : sW[(size_t)co * 147 + k];
    }
    g_pw3[idx] = f2bf(v);
  }
}

// ---------------- kernel 2: MFMA conv + LN + combine -> pixel-major scratch ---
// 896 blocks x 448 threads (7 waves). Same structure as R15; only the store
// target changes: scratch [b][tile][co][px16] (4x64B per instr, L2-local).
// direct==1 falls back to co-major out stores (ws too small).
__global__ __launch_bounds__(448, 3) void k_main(
    const float* __restrict__ x,
    const float* __restrict__ w_gate,
    const float* __restrict__ eB, const float* __restrict__ sB,
    const float* __restrict__ elnw, const float* __restrict__ elnb,
    const float* __restrict__ slnw, const float* __restrict__ slnb,
    float* __restrict__ ws, int direct,
    float* __restrict__ out, float* __restrict__ loss_out) {
  __shared__ __align__(16) ushort Wnd[3 * WR * PWL];   // 15312 B

  const int tid  = threadIdx.x;
  const int lane = tid & 63;
  const int w    = tid >> 6;      // 0..6 (tile within group)
  const int b    = blockIdx.x / NGRP;
  const int G    = blockIdx.x % NGRP;

  // ---- stage window: ih = 8G-3 .. 8G+7 per ci, cols padded +4/+4 ----
  for (int i = tid; i < 3 * WR * 28; i += 448) {
    const int j8 = i % 28;
    const int rr = i / 28;              // ci*11 + wr
    const int ci = rr / WR;
    const int wr = rr - ci * WR;
    const int ih = 8 * G + wr - 3;
    uint2 lo = {0u, 0u}, hi = {0u, 0u};
    if ((unsigned)ih < (unsigned)HIN) {
      const float4* xr = reinterpret_cast<const float4*>(
          x + ((size_t)(b * CIN + ci) * HIN + ih) * WIN);
      const float4 f0 = xr[2 * j8];
      const float4 f1 = xr[2 * j8 + 1];
      lo.x = (uint)f2bf(f0.x) | ((uint)f2bf(f0.y) << 16);
      lo.y = (uint)f2bf(f0.z) | ((uint)f2bf(f0.w) << 16);
      hi.x = (uint)f2bf(f1.x) | ((uint)f2bf(f1.y) << 16);
      hi.y = (uint)f2bf(f1.z) | ((uint)f2bf(f1.w) << 16);
    }
    *reinterpret_cast<uint2*>(&Wnd[rr * PWL + 8 * j8 + 4]) = lo;
    *reinterpret_cast<uint2*>(&Wnd[rr * PWL + 8 * j8 + 8]) = hi;
    if (j8 == 0)  { const uint2 z = {0u, 0u}; *reinterpret_cast<uint2*>(&Wnd[rr * PWL]) = z; }
    if (j8 == 27) { const uint2 z = {0u, 0u}; *reinterpret_cast<uint2*>(&Wnd[rr * PWL + 228]) = z; }
  }

  // ---- gating from partials (overlaps staging latency) ----
  float gi[3];
  #pragma unroll
  for (int c = 0; c < 3; ++c) {
    float s = 0.f;
    #pragma unroll
    for (int p = 0; p < 8; ++p) s += g_gatepart[(b * 3 + c) * 8 + p];
    gi[c] = s * (1.f / (float)(HIN * WIN));
  }
  float best1 = -1e30f, best2 = -1e30f;
  int i1 = 0, i2 = 0;
  #pragma unroll
  for (int e = 0; e < NEXP; ++e) {
    const float lg = gi[0] * w_gate[e] + gi[1] * w_gate[8 + e] + gi[2] * w_gate[16 + e];
    if (lg > best1) { best2 = best1; i2 = i1; best1 = lg; i1 = e; }
    else if (lg > best2) { best2 = lg; i2 = e; }
  }
  const float e21 = expf(best2 - best1);
  const float g1 = 1.f / (1.f + e21);
  const float g2 = e21 / (1.f + e21);
  const int e1 = __builtin_amdgcn_readfirstlane(i1);
  const int e2 = __builtin_amdgcn_readfirstlane(i2);

  // ---- aux loss: block 0, wave 0 (lane = image) ----
  if (blockIdx.x == 0 && w == 0) {
    float mg1 = 0.f, mg2 = 0.f;
    int me1 = -1, me2 = -1;
    if (lane < BATCH) {
      float a[3];
      #pragma unroll
      for (int c = 0; c < 3; ++c) {
        float s = 0.f;
        #pragma unroll
        for (int p = 0; p < 8; ++p) s += g_gatepart[(lane * 3 + c) * 8 + p];
        a[c] = s * (1.f / (float)(HIN * WIN));
      }
      float b1 = -1e30f, b2 = -1e30f;
      int j1 = 0, j2 = 0;
      #pragma unroll
      for (int e = 0; e < NEXP; ++e) {
        const float lg = a[0] * w_gate[e] + a[1] * w_gate[8 + e] + a[2] * w_gate[16 + e];
        if (lg > b1) { b2 = b1; j2 = j1; b1 = lg; j1 = e; }
        else if (lg > b2) { b2 = lg; j2 = e; }
      }
      const float q = expf(b2 - b1);
      mg1 = 1.f / (1.f + q); mg2 = q / (1.f + q);
      me1 = j1; me2 = j2;
    }
    float imp[NEXP], lod[NEXP];
    #pragma unroll
    for (int e = 0; e < NEXP; ++e) {
      float ie = ((me1 == e) ? mg1 : 0.f) + ((me2 == e) ? mg2 : 0.f);
      float le = (((me1 == e) && (mg1 > 0.f)) ? 1.f : 0.f)
               + (((me2 == e) && (mg2 > 0.f)) ? 1.f : 0.f);
      #pragma unroll
      for (int o = 32; o > 0; o >>= 1) { ie += __shfl_xor(ie, o, 64); le += __shfl_xor(le, o, 64); }
      imp[e] = ie; lod[e] = le;
    }
    if (lane == 0) {
      float mi = 0.f, ml = 0.f;
      #pragma unroll
      for (int e = 0; e < NEXP; ++e) { mi += imp[e]; ml += lod[e]; }
      mi *= (1.f / NEXP); ml *= (1.f / NEXP);
      float vi = 0.f, vl = 0.f;
      #pragma unroll
      for (int e = 0; e < NEXP; ++e) {
        const float di = imp[e] - mi; vi += di * di;
        const float dl = lod[e] - ml; vl += dl * dl;
      }
      vi *= (1.f / (NEXP - 1)); vl *= (1.f / (NEXP - 1));
      loss_out[0] = 0.01f * (vi / (mi * mi + 1e-10f) + vl / (ml * ml + 1e-10f));
    }
  }

  const int m    = lane >> 4;       // k-chunk / co-subrow group
  const int colA = lane & 15;       // pixel within tile
  const int eidx[3] = {e1, e2, 8};
  const float ge[3] = {g1, g2, 1.f};

  // per-lane window row offsets per ks (k' row r = 4ks+m; r>20 clamps, wt=0)
  int Crow[NKS];
  #pragma unroll
  for (int ks = 0; ks < NKS; ++ks) {
    int r = 4 * ks + m;
    r = r > 20 ? 20 : r;
    const int ci = r >= 14 ? 2 : (r >= 7 ? 1 : 0);
    const int kh = r - ci * 7;
    Crow[ks] = (ci * WR + kh) * PWL;
  }

  // my single pixel-tile
  const int tile = G * 7 + w;               // 0..195
  const int pg = tile * 16 + colA;          // global pixel in image
  const int oh = pg / WOUT;
  const int ow = pg - oh * WOUT;
  const int baseB = ((oh - 2 * G) * 4) * PWL + ow * 4;

  __syncthreads();   // window visible; waves independent from here on

  float outAcc[16];
  #pragma unroll
  for (int j = 0; j < 16; ++j) outAcc[j] = 0.f;

  // ---- expert-outer loop (no barriers, no LDS besides B-reads) ----
  #pragma unroll
  for (int e = 0; e < 3; ++e) {
    const int es = eidx[e];
    f32x4 acc[4];
    #pragma unroll
    for (int f = 0; f < 4; ++f) acc[f] = (f32x4){0.f, 0.f, 0.f, 0.f};

    const ushort* ape = g_pw3 + (size_t)es * (4 * 6 * 512) + lane * 8;
    #pragma unroll
    for (int ks = 0; ks < NKS; ++ks) {
      bf16x8 a4[4];
      #pragma unroll
      for (int f = 0; f < 4; ++f)
        a4[f] = __builtin_bit_cast(bf16x8, *reinterpret_cast<const uint4*>(
            ape + (f * 6 + ks) * 512));
      const ushort* p = &Wnd[baseB + Crow[ks]];
      const uint2 lo = *reinterpret_cast<const uint2*>(p);
      const uint2 hi = *reinterpret_cast<const uint2*>(p + 4);
      const uint4 raw = {lo.x, lo.y, hi.x, hi.y};
      const bf16x8 bf = __builtin_bit_cast(bf16x8, raw);
      #pragma unroll
      for (int f = 0; f < 4; ++f)
        acc[f] = __builtin_amdgcn_mfma_f32_16x16x32_bf16(a4[f], bf, acc[f], 0, 0, 0);
    }

    // bias + wave-local LN stats
    const float* bsrc = (e < 2) ? eB + es * COUT : sB;
    const float* wsrc = (e < 2) ? elnw + es * COUT : slnw;
    const float* csrc = (e < 2) ? elnb + es * COUT : slnb;
    float s = 0.f, q = 0.f;
    #pragma unroll
    for (int f = 0; f < 4; ++f) {
      const float4 b4 = *reinterpret_cast<const float4*>(bsrc + f * 16 + m * 4);
      #pragma unroll
      for (int r = 0; r < 4; ++r) {
        const float y = acc[f][r] + (&b4.x)[r];
        acc[f][r] = y;
        s += y; q += y * y;
      }
    }
    s += __shfl_xor(s, 16, 64); s += __shfl_xor(s, 32, 64);
    q += __shfl_xor(q, 16, 64); q += __shfl_xor(q, 32, 64);
    const float u  = s * (1.f / 64.f);
    const float vv = q * (1.f / 64.f) - u * u;
    const float rs = rsqrtf(vv + LN_EPS_F);
    #pragma unroll
    for (int f = 0; f < 4; ++f) {
      const float4 lw4 = *reinterpret_cast<const float4*>(wsrc + f * 16 + m * 4);
      const float4 lb4 = *reinterpret_cast<const float4*>(csrc + f * 16 + m * 4);
      #pragma unroll
      for (int r = 0; r < 4; ++r)
        outAcc[f * 4 + r] += ge[e] * ((&lw4.x)[r] * (acc[f][r] - u) * rs + (&lb4.x)[r]);
    }
  }

  if (direct) {
    // fallback: co-major stores straight to out (R15 behavior)
    float* const outb = out + (size_t)b * (COUT * NPIX);
    #pragma unroll
    for (int f = 0; f < 4; ++f)
      #pragma unroll
      for (int r = 0; r < 4; ++r)
        __builtin_nontemporal_store(outAcc[f * 4 + r],
            outb + (size_t)(f * 16 + m * 4 + r) * NPIX + pg);
  } else {
    // pixel-major scratch: [b][tile][co][px16] — 4x64B per instr, L2-local
    float* const wsb = ws + ((size_t)(b * NTILE + tile) * COUT) * 16;
    #pragma unroll
    for (int f = 0; f < 4; ++f)
      #pragma unroll
      for (int r = 0; r < 4; ++r)
        wsb[(f * 16 + m * 4 + r) * 16 + colA] = outAcc[f * 4 + r];
  }
}

// ---------------- kernel 3: streaming transpose scratch -> out ----------------
// 512 blocks x 256 threads. Block (b, cg): 4 co-planes, each written fully
// sequentially (float4/thread, 1KB/instr/wave) — DRAM-page-friendly stream.
__global__ __launch_bounds__(256) void k_out(const float* __restrict__ ws,
                                             float* __restrict__ out) {
  const int b  = blockIdx.x >> 4;
  const int cg = blockIdx.x & 15;
  const int tid = threadIdx.x;
  const float* wsb = ws + (size_t)b * NTILE * COUT * 16;
  float* outb = out + (size_t)b * (COUT * NPIX);
  #pragma unroll
  for (int cc = 0; cc < 4; ++cc) {
    const int co = cg * 4 + cc;
    for (int i = tid; i < NPIX / 4; i += 256) {     // 784 float4 per plane
      const int px = i * 4;
      const int t  = px >> 4;
      const int j  = px & 15;
      const float4 v = *reinterpret_cast<const float4*>(wsb + (size_t)(t * COUT + co) * 16 + j);
      *reinterpret_cast<float4*>(outb + (size_t)co * NPIX + px) = v;
    }
  }
}

// ---------------- launch ----------------
extern "C" void kernel_launch(void* const* d_in, const int* in_sizes, int n_in,
                              void* d_out, int out_size, void* d_ws, size_t ws_size,
                              hipStream_t stream) {
  const float* x    = (const float*)d_in[0];
  const float* eW   = (const float*)d_in[1];
  const float* eB   = (const float*)d_in[2];
  const float* elnw = (const float*)d_in[3];
  const float* elnb = (const float*)d_in[4];
  const float* sW   = (const float*)d_in[5];
  const float* sB   = (const float*)d_in[6];
  const float* slnw = (const float*)d_in[7];
  const float* slnb = (const float*)d_in[8];
  const float* wg   = (const float*)d_in[9];
  float* out = (float*)d_out;
  float* ws  = (float*)d_ws;

  float* loss_ptr = out + (size_t)BATCH * COUT * NPIX;  // element 6422528
  const int direct = (ws_size < WS_NEED) ? 1 : 0;

  k_pre<<<N_GPART + N_REPACK, 256, 0, stream>>>(x, eW, sW);
  k_main<<<BATCH * NGRP, 448, 0, stream>>>(x, wg, eB, sB, elnw, elnb,
                                           slnw, slnb, ws, direct, out, loss_ptr);
  if (!direct) {
    k_out<<<BATCH * 16, 256, 0, stream>>>(ws, out);
  }
}

// Round 17
// 43.587 us; speedup vs baseline: 1.3267x; 1.3267x over previous
//
#include <hip/hip_runtime.h>
#include <cstdint>
#include <cstddef>

// ---- problem constants ----
static constexpr int BATCH = 32;
static constexpr int CIN   = 3;
static constexpr int HIN   = 224, WIN = 224;
static constexpr int COUT  = 64;
static constexpr int HOUT  = 56, WOUT = 56;
static constexpr int NPIX  = HOUT * WOUT;     // 3136
static constexpr int NEXP  = 8;
static constexpr int KROWS = 21;              // ci*7 + kh
static constexpr int NKS   = 6;               // K-steps of 32
static constexpr int NGRP  = 28;              // 2-oh-row groups per image (112 px)
static constexpr int PWL   = 232;             // window row length (ushorts): 4+224+4
static constexpr int WR    = 11;              // window rows per ci (2*4 + 3)
static constexpr float LN_EPS_F = 1e-6f;

// fragment-coalesced weight buffer: [e(9)][f(4)][ks(6)][lane(64)][8]
static constexpr int PW3_ELEMS = 9 * 4 * 6 * 64 * 8;   // 110592

// k_pre partition: gate partial sums (768) + weight repack (432)
static constexpr int N_GPART  = BATCH * CIN * 8;                  // 768
static constexpr int N_REPACK = (PW3_ELEMS + 255) / 256;          // 432

typedef __bf16 bf16x8 __attribute__((ext_vector_type(8)));
typedef float  f32x4  __attribute__((ext_vector_type(4)));

// ---- device-global scratch ----
__device__ __align__(16) ushort g_pw3[PW3_ELEMS];   // bf16 weights, fragment order
__device__ float g_gatepart[BATCH * CIN * 8];       // partial plane sums

__device__ __forceinline__ ushort f2bf(float f) {
  uint u = __float_as_uint(f);
  uint r = (u + 0x7FFFu + ((u >> 16) & 1u)) >> 16;  // RNE
  return (ushort)r;
}

// ---------------- kernel 1: gate partial sums (0..767) / repack (768..1199) ---
__global__ __launch_bounds__(256) void k_pre(const float* __restrict__ x,
                                             const float* __restrict__ eW,
                                             const float* __restrict__ sW) {
  const int bid = blockIdx.x;
  if (bid < N_GPART) {
    const int plane = bid >> 3;
    const int slice = bid & 7;
    const float4* p4 = reinterpret_cast<const float4*>(x + (size_t)plane * (HIN * WIN));
    float s = 0.f;
    const int i0 = slice * 1568;                // 12544/8 float4 per slice
    for (int i = i0 + (int)threadIdx.x; i < i0 + 1568; i += 256) {
      const float4 v = p4[i];
      s += v.x + v.y + v.z + v.w;
    }
    __shared__ float red[256];
    red[threadIdx.x] = s;
    __syncthreads();
    for (int off = 128; off > 0; off >>= 1) {
      if ((int)threadIdx.x < off) red[threadIdx.x] += red[threadIdx.x + off];
      __syncthreads();
    }
    if (threadIdx.x == 0) g_gatepart[bid] = red[0];
  } else {
    // repack -> fragment order: idx = ((e*4+f)*6+ks)*512 + lane*8 + j
    const int idx = (bid - N_GPART) * 256 + threadIdx.x;
    if (idx >= PW3_ELEMS) return;
    const int j    = idx & 7;
    const int lane = (idx >> 3) & 63;
    const int ks   = (idx >> 9) % 6;
    const int fe   = idx / (512 * 6);   // e*4 + f
    const int f    = fe & 3;
    const int e    = fe >> 2;
    const int m    = lane >> 4;
    const int colA = lane & 15;
    const int co   = f * 16 + colA;
    const int r    = ks * 4 + m;
    float v = 0.f;
    if (j >= 1 && r < KROWS) {
      const int k = r * 7 + (j - 1);
      v = (e < 8) ? eW[(size_t)(e * COUT + co) * 147 + k]
                  : sW[(size_t)co * 147 + k];
    }
    g_pw3[idx] = f2bf(v);
  }
}

// ---------------- kernel 2: MFMA conv + LN + combine (R15 + A-pipeline + prio)
// 896 blocks x 448 threads (7 waves). Block (b,G): oh in [2G, 2G+2) = 112 px.
// Wave = 16 px x all 64 co; LN wave-local; one barrier total. Changes vs R15:
// (1) 2-deep A-fragment software pipeline (load ks+1 while MFMAs of ks run),
// (2) s_setprio(1) around the compute region. Nontemporal direct stores.
__global__ __launch_bounds__(448, 3) void k_main(
    const float* __restrict__ x,
    const float* __restrict__ w_gate,
    const float* __restrict__ eB, const float* __restrict__ sB,
    const float* __restrict__ elnw, const float* __restrict__ elnb,
    const float* __restrict__ slnw, const float* __restrict__ slnb,
    float* __restrict__ out, float* __restrict__ loss_out) {
  __shared__ __align__(16) ushort Wnd[3 * WR * PWL];   // 15312 B

  const int tid  = threadIdx.x;
  const int lane = tid & 63;
  const int w    = tid >> 6;      // 0..6 (tile within group)
  const int b    = blockIdx.x / NGRP;
  const int G    = blockIdx.x % NGRP;

  // ---- stage window: ih = 8G-3 .. 8G+7 per ci, cols padded +4/+4 ----
  for (int i = tid; i < 3 * WR * 28; i += 448) {
    const int j8 = i % 28;
    const int rr = i / 28;              // ci*11 + wr
    const int ci = rr / WR;
    const int wr = rr - ci * WR;
    const int ih = 8 * G + wr - 3;
    uint2 lo = {0u, 0u}, hi = {0u, 0u};
    if ((unsigned)ih < (unsigned)HIN) {
      const float4* xr = reinterpret_cast<const float4*>(
          x + ((size_t)(b * CIN + ci) * HIN + ih) * WIN);
      const float4 f0 = xr[2 * j8];
      const float4 f1 = xr[2 * j8 + 1];
      lo.x = (uint)f2bf(f0.x) | ((uint)f2bf(f0.y) << 16);
      lo.y = (uint)f2bf(f0.z) | ((uint)f2bf(f0.w) << 16);
      hi.x = (uint)f2bf(f1.x) | ((uint)f2bf(f1.y) << 16);
      hi.y = (uint)f2bf(f1.z) | ((uint)f2bf(f1.w) << 16);
    }
    *reinterpret_cast<uint2*>(&Wnd[rr * PWL + 8 * j8 + 4]) = lo;
    *reinterpret_cast<uint2*>(&Wnd[rr * PWL + 8 * j8 + 8]) = hi;
    if (j8 == 0)  { const uint2 z = {0u, 0u}; *reinterpret_cast<uint2*>(&Wnd[rr * PWL]) = z; }
    if (j8 == 27) { const uint2 z = {0u, 0u}; *reinterpret_cast<uint2*>(&Wnd[rr * PWL + 228]) = z; }
  }

  // ---- gating from partials (overlaps staging latency) ----
  float gi[3];
  #pragma unroll
  for (int c = 0; c < 3; ++c) {
    float s = 0.f;
    #pragma unroll
    for (int p = 0; p < 8; ++p) s += g_gatepart[(b * 3 + c) * 8 + p];
    gi[c] = s * (1.f / (float)(HIN * WIN));
  }
  float best1 = -1e30f, best2 = -1e30f;
  int i1 = 0, i2 = 0;
  #pragma unroll
  for (int e = 0; e < NEXP; ++e) {
    const float lg = gi[0] * w_gate[e] + gi[1] * w_gate[8 + e] + gi[2] * w_gate[16 + e];
    if (lg > best1) { best2 = best1; i2 = i1; best1 = lg; i1 = e; }
    else if (lg > best2) { best2 = lg; i2 = e; }
  }
  const float e21 = expf(best2 - best1);
  const float g1 = 1.f / (1.f + e21);
  const float g2 = e21 / (1.f + e21);
  const int e1 = __builtin_amdgcn_readfirstlane(i1);
  const int e2 = __builtin_amdgcn_readfirstlane(i2);

  // ---- aux loss: block 0, wave 0 (lane = image) ----
  if (blockIdx.x == 0 && w == 0) {
    float mg1 = 0.f, mg2 = 0.f;
    int me1 = -1, me2 = -1;
    if (lane < BATCH) {
      float a[3];
      #pragma unroll
      for (int c = 0; c < 3; ++c) {
        float s = 0.f;
        #pragma unroll
        for (int p = 0; p < 8; ++p) s += g_gatepart[(lane * 3 + c) * 8 + p];
        a[c] = s * (1.f / (float)(HIN * WIN));
      }
      float b1 = -1e30f, b2 = -1e30f;
      int j1 = 0, j2 = 0;
      #pragma unroll
      for (int e = 0; e < NEXP; ++e) {
        const float lg = a[0] * w_gate[e] + a[1] * w_gate[8 + e] + a[2] * w_gate[16 + e];
        if (lg > b1) { b2 = b1; j2 = j1; b1 = lg; j1 = e; }
        else if (lg > b2) { b2 = lg; j2 = e; }
      }
      const float q = expf(b2 - b1);
      mg1 = 1.f / (1.f + q); mg2 = q / (1.f + q);
      me1 = j1; me2 = j2;
    }
    float imp[NEXP], lod[NEXP];
    #pragma unroll
    for (int e = 0; e < NEXP; ++e) {
      float ie = ((me1 == e) ? mg1 : 0.f) + ((me2 == e) ? mg2 : 0.f);
      float le = (((me1 == e) && (mg1 > 0.f)) ? 1.f : 0.f)
               + (((me2 == e) && (mg2 > 0.f)) ? 1.f : 0.f);
      #pragma unroll
      for (int o = 32; o > 0; o >>= 1) { ie += __shfl_xor(ie, o, 64); le += __shfl_xor(le, o, 64); }
      imp[e] = ie; lod[e] = le;
    }
    if (lane == 0) {
      float mi = 0.f, ml = 0.f;
      #pragma unroll
      for (int e = 0; e < NEXP; ++e) { mi += imp[e]; ml += lod[e]; }
      mi *= (1.f / NEXP); ml *= (1.f / NEXP);
      float vi = 0.f, vl = 0.f;
      #pragma unroll
      for (int e = 0; e < NEXP; ++e) {
        const float di = imp[e] - mi; vi += di * di;
        const float dl = lod[e] - ml; vl += dl * dl;
      }
      vi *= (1.f / (NEXP - 1)); vl *= (1.f / (NEXP - 1));
      loss_out[0] = 0.01f * (vi / (mi * mi + 1e-10f) + vl / (ml * ml + 1e-10f));
    }
  }

  const int m    = lane >> 4;       // k-chunk / co-subrow group
  const int colA = lane & 15;       // pixel within tile
  const int eidx[3] = {e1, e2, 8};
  const float ge[3] = {g1, g2, 1.f};

  // per-lane window row offsets per ks (k' row r = 4ks+m; r>20 clamps, wt=0)
  int Crow[NKS];
  #pragma unroll
  for (int ks = 0; ks < NKS; ++ks) {
    int r = 4 * ks + m;
    r = r > 20 ? 20 : r;
    const int ci = r >= 14 ? 2 : (r >= 7 ? 1 : 0);
    const int kh = r - ci * 7;
    Crow[ks] = (ci * WR + kh) * PWL;
  }

  // my single pixel-tile
  const int pg = G * 112 + w * 16 + colA;   // global pixel in image
  const int oh = pg / WOUT;
  const int ow = pg - oh * WOUT;
  const int baseB = ((oh - 2 * G) * 4) * PWL + ow * 4;

  __syncthreads();   // window visible; waves independent from here on

  __builtin_amdgcn_s_setprio(1);

  float outAcc[16];
  #pragma unroll
  for (int j = 0; j < 16; ++j) outAcc[j] = 0.f;

  // ---- expert-outer loop with 2-deep A-load pipeline ----
  #pragma unroll
  for (int e = 0; e < 3; ++e) {
    const int es = eidx[e];
    f32x4 acc[4];
    #pragma unroll
    for (int f = 0; f < 4; ++f) acc[f] = (f32x4){0.f, 0.f, 0.f, 0.f};

    const ushort* ape = g_pw3 + (size_t)es * (4 * 6 * 512) + lane * 8;

    // prologue: load ks=0 fragments
    bf16x8 aCur0 = __builtin_bit_cast(bf16x8, *reinterpret_cast<const uint4*>(ape + (0 * 6 + 0) * 512));
    bf16x8 aCur1 = __builtin_bit_cast(bf16x8, *reinterpret_cast<const uint4*>(ape + (1 * 6 + 0) * 512));
    bf16x8 aCur2 = __builtin_bit_cast(bf16x8, *reinterpret_cast<const uint4*>(ape + (2 * 6 + 0) * 512));
    bf16x8 aCur3 = __builtin_bit_cast(bf16x8, *reinterpret_cast<const uint4*>(ape + (3 * 6 + 0) * 512));

    #pragma unroll
    for (int ks = 0; ks < NKS; ++ks) {
      // issue next ks's A-loads before consuming current (latency overlap)
      bf16x8 aNxt0, aNxt1, aNxt2, aNxt3;
      if (ks < NKS - 1) {
        aNxt0 = __builtin_bit_cast(bf16x8, *reinterpret_cast<const uint4*>(ape + (0 * 6 + ks + 1) * 512));
        aNxt1 = __builtin_bit_cast(bf16x8, *reinterpret_cast<const uint4*>(ape + (1 * 6 + ks + 1) * 512));
        aNxt2 = __builtin_bit_cast(bf16x8, *reinterpret_cast<const uint4*>(ape + (2 * 6 + ks + 1) * 512));
        aNxt3 = __builtin_bit_cast(bf16x8, *reinterpret_cast<const uint4*>(ape + (3 * 6 + ks + 1) * 512));
      }
      const ushort* p = &Wnd[baseB + Crow[ks]];
      const uint2 lo = *reinterpret_cast<const uint2*>(p);
      const uint2 hi = *reinterpret_cast<const uint2*>(p + 4);
      const uint4 raw = {lo.x, lo.y, hi.x, hi.y};
      const bf16x8 bf = __builtin_bit_cast(bf16x8, raw);
      acc[0] = __builtin_amdgcn_mfma_f32_16x16x32_bf16(aCur0, bf, acc[0], 0, 0, 0);
      acc[1] = __builtin_amdgcn_mfma_f32_16x16x32_bf16(aCur1, bf, acc[1], 0, 0, 0);
      acc[2] = __builtin_amdgcn_mfma_f32_16x16x32_bf16(aCur2, bf, acc[2], 0, 0, 0);
      acc[3] = __builtin_amdgcn_mfma_f32_16x16x32_bf16(aCur3, bf, acc[3], 0, 0, 0);
      if (ks < NKS - 1) { aCur0 = aNxt0; aCur1 = aNxt1; aCur2 = aNxt2; aCur3 = aNxt3; }
    }

    // bias + wave-local LN stats
    const float* bsrc = (e < 2) ? eB + es * COUT : sB;
    const float* wsrc = (e < 2) ? elnw + es * COUT : slnw;
    const float* csrc = (e < 2) ? elnb + es * COUT : slnb;
    float s = 0.f, q = 0.f;
    #pragma unroll
    for (int f = 0; f < 4; ++f) {
      const float4 b4 = *reinterpret_cast<const float4*>(bsrc + f * 16 + m * 4);
      #pragma unroll
      for (int r = 0; r < 4; ++r) {
        const float y = acc[f][r] + (&b4.x)[r];
        acc[f][r] = y;
        s += y; q += y * y;
      }
    }
    s += __shfl_xor(s, 16, 64); s += __shfl_xor(s, 32, 64);
    q += __shfl_xor(q, 16, 64); q += __shfl_xor(q, 32, 64);
    const float u  = s * (1.f / 64.f);
    const float vv = q * (1.f / 64.f) - u * u;
    const float rs = rsqrtf(vv + LN_EPS_F);
    #pragma unroll
    for (int f = 0; f < 4; ++f) {
      const float4 lw4 = *reinterpret_cast<const float4*>(wsrc + f * 16 + m * 4);
      const float4 lb4 = *reinterpret_cast<const float4*>(csrc + f * 16 + m * 4);
      #pragma unroll
      for (int r = 0; r < 4; ++r)
        outAcc[f * 4 + r] += ge[e] * ((&lw4.x)[r] * (acc[f][r] - u) * rs + (&lb4.x)[r]);
    }
  }

  __builtin_amdgcn_s_setprio(0);

  // ---- NONTEMPORAL stores: co = f*16 + m*4 + r, pixel pg ----
  float* const outb = out + (size_t)b * (COUT * NPIX);
  #pragma unroll
  for (int f = 0; f < 4; ++f)
    #pragma unroll
    for (int r = 0; r < 4; ++r)
      __builtin_nontemporal_store(outAcc[f * 4 + r],
          outb + (size_t)(f * 16 + m * 4 + r) * NPIX + pg);
}

// ---------------- launch ----------------
extern "C" void kernel_launch(void* const* d_in, const int* in_sizes, int n_in,
                              void* d_out, int out_size, void* d_ws, size_t ws_size,
                              hipStream_t stream) {
  const float* x    = (const float*)d_in[0];
  const float* eW   = (const float*)d_in[1];
  const float* eB   = (const float*)d_in[2];
  const float* elnw = (const float*)d_in[3];
  const float* elnb = (const float*)d_in[4];
  const float* sW   = (const float*)d_in[5];
  const float* sB   = (const float*)d_in[6];
  const float* slnw = (const float*)d_in[7];
  const float* slnb = (const float*)d_in[8];
  const float* wg   = (const float*)d_in[9];
  float* out = (float*)d_out;

  float* loss_ptr = out + (size_t)BATCH * COUT * NPIX;  // element 6422528

  k_pre<<<N_GPART + N_REPACK, 256, 0, stream>>>(x, eW, sW);
  k_main<<<BATCH * NGRP, 448, 0, stream>>>(x, wg, eB, sB, elnw, elnb,
                                           slnw, slnb, out, loss_ptr);
}